// Round 13
// baseline (844.632 us; speedup 1.0000x reference)
//
#include <hip/hip_runtime.h>
#include <stdint.h>

#define B_DIM 512
#define I_DIM 128
#define H_DIM 128
#define NSTEP 511   // reference scans t = 0..T-2

typedef __attribute__((ext_vector_type(4))) float f32x4;
typedef _Float16 half2_t __attribute__((ext_vector_type(2)));
typedef _Float16 half8_t __attribute__((ext_vector_type(8)));

// Barrier draining ONLY LDS ops; global prefetches stay in flight across it.
#define BAR_LDS() asm volatile("s_waitcnt lgkmcnt(0)\n\ts_barrier" ::: "memory")

#define MFMA16(A, B, C) __builtin_amdgcn_mfma_f32_16x16x32_f16(A, B, C, 0, 0, 0)

// ---------------------------------------------------------------------------
// Persistent fused GRU: 32 blocks x 16 batch rows, 512 threads (8 work
// waves, 2/SIMD). ALL 511 steps in one dispatch; h never leaves the block.
//
// Round-13 deltas vs round 12 (which measured ~90% stall/step):
//  * x staged from a register loaded TWO steps earlier (rotating xA/xB);
//    the load for x(s+3) is issued at step s -> ~2 full steps of slack,
//    so the cold-HBM latency (~900cy, amplified by the post-barrier burst)
//    is fully hidden and the stage write's vmcnt wait is ~0.
//  * aR/aZ split into h/x accumulator pairs: MFMA dep chain 8 -> 4 deep.
//  * wave-0 decode+NLL moved after the stage write (overlaps the other
//    waves' barrier arrival instead of gating it).
// ---------------------------------------------------------------------------
__global__ __launch_bounds__(512, 2) void k_rec(
    const float* __restrict__ x, const float* __restrict__ gt,
    const float* __restrict__ Wih, const float* __restrict__ Whh,
    const float* __restrict__ bih, const float* __restrict__ bhh,
    const float* __restrict__ Wdec, const float* __restrict__ bdec,
    float* __restrict__ nll_part) {
  __shared__ __align__(16) _Float16 hT[2][16 * 128];  // 8 KB, dbuf h tiles
  __shared__ __align__(16) _Float16 xT[2][16 * 128];  // 8 KB, dbuf x tiles
  __shared__ float gl[NSTEP * 16];                    // 32 KB gt slice

  const int tid = threadIdx.x;
  const int lane = tid & 63;
  const int w = tid >> 6;
  const int l15 = lane & 15, l4 = lane >> 4;
  const int row0 = blockIdx.x * 16;
  const int u = 16 * w + l15;          // unit this lane owns

  // x-staging identity: thread -> (row, 4-float chunk); swizzled byte addr
  const int sxr = tid >> 5;            // row in [0,16)
  const int scq = tid & 31;            // col chunk
  const int sbyte = sxr * 256 + (((scq >> 1) ^ sxr) << 4) + (scq & 1) * 8;
  const size_t xbase = ((size_t)row0 + sxr) * I_DIM + 4 * scq;

  // ---- one-time: B-fragments (f16) for Whh and Wih ----
  half8_t bh[3][4], bx[3][4];
#pragma unroll
  for (int g3 = 0; g3 < 3; ++g3) {
#pragma unroll
    for (int ks = 0; ks < 4; ++ks) {
      const size_t off = (size_t)(g3 * H_DIM + u) * H_DIM + ks * 32 + l4 * 8;
      float4 a = *(const float4*)(Whh + off);
      float4 b = *(const float4*)(Whh + off + 4);
      half8_t v;
      v[0] = (_Float16)a.x; v[1] = (_Float16)a.y;
      v[2] = (_Float16)a.z; v[3] = (_Float16)a.w;
      v[4] = (_Float16)b.x; v[5] = (_Float16)b.y;
      v[6] = (_Float16)b.z; v[7] = (_Float16)b.w;
      bh[g3][ks] = v;
      a = *(const float4*)(Wih + off);
      b = *(const float4*)(Wih + off + 4);
      v[0] = (_Float16)a.x; v[1] = (_Float16)a.y;
      v[2] = (_Float16)a.z; v[3] = (_Float16)a.w;
      v[4] = (_Float16)b.x; v[5] = (_Float16)b.y;
      v[6] = (_Float16)b.z; v[7] = (_Float16)b.w;
      bx[g3][ks] = v;
    }
  }
  // W_dec as B-fragment col 0 (decode via MFMA on wave 0)
  half8_t wdB[4];
#pragma unroll
  for (int ks = 0; ks < 4; ++ks) {
    half8_t v;
#pragma unroll
    for (int j = 0; j < 8; ++j)
      v[j] = (l15 == 0) ? (_Float16)Wdec[ks * 32 + l4 * 8 + j] : (_Float16)0.f;
    wdB[ks] = v;
  }
  const float brz0 = bih[u] + bhh[u];                    // r-gate bias
  const float brz1 = bih[H_DIM + u] + bhh[H_DIM + u];    // z-gate bias
  const float bxn = bih[2 * H_DIM + u];                  // n-gate x-side
  const float bhn = bhh[2 * H_DIM + u];                  // n-gate h-side
  const float bd0 = bdec[0];

  // ---- gt preload: gl[s*16 + c] = gt[s+1][row0+c] ----
#pragma unroll
  for (int q = 0; q < 16; ++q) {
    const int idx = tid + 512 * q;
    if (idx < NSTEP * 16)
      gl[idx] = gt[(size_t)((idx >> 4) + 1) * B_DIM + row0 + (idx & 15)];
  }

  // ---- zero h(0) tile; stage x(0); preload x(1), x(2) into registers ----
  {
    *(uint2*)((char*)hT[0] + sbyte) = (uint2){0u, 0u};
    const float4 xv = *(const float4*)&x[xbase];
    half2_t p0, p1;
    p0.x = (_Float16)xv.x; p0.y = (_Float16)xv.y;
    p1.x = (_Float16)xv.z; p1.y = (_Float16)xv.w;
    uint2 pk;
    pk.x = __builtin_bit_cast(unsigned, p0);
    pk.y = __builtin_bit_cast(unsigned, p1);
    *(uint2*)((char*)xT[0] + sbyte) = pk;
  }
  float4 xA = *(const float4*)&x[(size_t)1 * B_DIM * I_DIM + xbase];  // x(1)
  float4 xB = *(const float4*)&x[(size_t)2 * B_DIM * I_DIM + xbase];  // x(2)
  float h_old[4] = {0.f, 0.f, 0.f, 0.f};
  float nllA[4] = {0.f, 0.f, 0.f, 0.f};
  __syncthreads();

#pragma unroll 1
  for (int s = 0; s < NSTEP; ++s) {
    // A-fragments for h(s) and x(s), XOR-swizzled (blk ^ row)
    const char* hb = (const char*)hT[s & 1];
    const char* xb = (const char*)xT[s & 1];
    half8_t ah[4], ax[4];
#pragma unroll
    for (int ks = 0; ks < 4; ++ks) {
      const int ab = l15 * 256 + ((((ks << 2) | l4) ^ l15) << 4);
      ah[ks] = *(const half8_t*)(hb + ab);
      ax[ks] = *(const half8_t*)(xb + ab);
    }

    // 24 MFMA; h/x accumulators split (4-deep chains), merged in VALU
    f32x4 aRh = (f32x4){0.f, 0.f, 0.f, 0.f}, aRx = aRh;
    f32x4 aZh = aRh, aZx = aRh, aNh = aRh, aNx = aRh;
#pragma unroll
    for (int ks = 0; ks < 4; ++ks) {
      aRh = MFMA16(ah[ks], bh[0][ks], aRh);
      aRx = MFMA16(ax[ks], bx[0][ks], aRx);
      aZh = MFMA16(ah[ks], bh[1][ks], aZh);
      aZx = MFMA16(ax[ks], bx[1][ks], aZx);
      aNh = MFMA16(ah[ks], bh[2][ks], aNh);
      aNx = MFMA16(ax[ks], bx[2][ks], aNx);
    }

    // gate math, lane-local; write hnew (b16) into the other h tile
    char* hw = (char*)hT[(s + 1) & 1];
#pragma unroll
    for (int r = 0; r < 4; ++r) {
      const float rp = (aRh[r] + aRx[r]) + brz0;
      const float zp = (aZh[r] + aZx[r]) + brz1;
      const float r_ = 1.f / (1.f + __expf(-rp));
      const float z_ = 1.f / (1.f + __expf(-zp));
      const float a2 = (aNx[r] + bxn) + r_ * (aNh[r] + bhn);
      const float e2 = __expf(2.f * a2);
      const float n_ = 1.f - 2.f / (e2 + 1.f);
      const float hnew = (1.f - z_) * n_ + z_ * h_old[r];
      h_old[r] = hnew;
      const int b = 4 * l4 + r;
      *(_Float16*)(hw + b * 256 + (((u >> 3) ^ b) << 4) + (u & 7) * 2) =
          (_Float16)hnew;
    }

    // stage x(s+1) from xA (loaded 2 steps ago -> vmcnt wait ~0);
    // rotate and issue the load for x(s+3) (clamped; x has 512 rows)
    {
      half2_t p0, p1;
      p0.x = (_Float16)xA.x; p0.y = (_Float16)xA.y;
      p1.x = (_Float16)xA.z; p1.y = (_Float16)xA.w;
      uint2 pk;
      pk.x = __builtin_bit_cast(unsigned, p0);
      pk.y = __builtin_bit_cast(unsigned, p1);
      *(uint2*)((char*)xT[(s + 1) & 1] + sbyte) = pk;
      xA = xB;
      const int nfetch = (s + 3 < 512) ? s + 3 : 511;
      xB = *(const float4*)&x[(size_t)nfetch * B_DIM * I_DIM + xbase];
    }

    // decode + NLL for h(s) vs gt[s] on wave 0 (after stage: overlaps the
    // other waves' barrier arrival). Uses this step's ah regs.
    if (w == 0 && s > 0) {
      f32x4 aD = (f32x4){0.f, 0.f, 0.f, 0.f};
#pragma unroll
      for (int ks = 0; ks < 4; ++ks) aD = MFMA16(ah[ks], wdB[ks], aD);
      if (l15 == 0) {
#pragma unroll
        for (int r = 0; r < 4; ++r) {
          const float C = 1.f / (1.f + __expf(-(aD[r] + bd0)));
          const float g = gl[(s - 1) * 16 + 4 * l4 + r];
          nllA[r] -= g * __logf(C + 1e-4f) +
                     (1.f - g) * __logf(1.f - C + 1e-4f);
        }
      }
    }
    BAR_LDS();  // the ONE barrier: h(s+1) + x(s+1) published
  }

  // ---- epilogue: decode h(511) vs gt[511]; write per-row NLL ----
  if (w == 0) {
    const char* hb = (const char*)hT[NSTEP & 1];
    half8_t ah[4];
#pragma unroll
    for (int ks = 0; ks < 4; ++ks)
      ah[ks] = *(const half8_t*)(hb + l15 * 256 +
                                 ((((ks << 2) | l4) ^ l15) << 4));
    f32x4 aD = (f32x4){0.f, 0.f, 0.f, 0.f};
#pragma unroll
    for (int ks = 0; ks < 4; ++ks) aD = MFMA16(ah[ks], wdB[ks], aD);
    if (l15 == 0) {
#pragma unroll
      for (int r = 0; r < 4; ++r) {
        const float C = 1.f / (1.f + __expf(-(aD[r] + bd0)));
        const float g = gl[(NSTEP - 1) * 16 + 4 * l4 + r];
        nllA[r] -= g * __logf(C + 1e-4f) +
                   (1.f - g) * __logf(1.f - C + 1e-4f);
        nll_part[row0 + 4 * l4 + r] = nllA[r];
      }
    }
  }
}

// ---------------------------------------------------------------------------
__global__ __launch_bounds__(512) void k_fin(const float* __restrict__ nll_part,
                                             float* __restrict__ out) {
  __shared__ float red[8];
  const int tid = threadIdx.x;
  float v = nll_part[tid];
#pragma unroll
  for (int off = 32; off; off >>= 1) v += __shfl_down(v, off);
  if ((tid & 63) == 0) red[tid >> 6] = v;
  __syncthreads();
  if (tid == 0) {
    float s = 0.f;
#pragma unroll
    for (int i = 0; i < 8; ++i) s += red[i];
    out[0] = s * (1.f / (512.f * 512.f));
  }
}

// ---------------------------------------------------------------------------
extern "C" void kernel_launch(void* const* d_in, const int* in_sizes, int n_in,
                              void* d_out, int out_size, void* d_ws,
                              size_t ws_size, hipStream_t stream) {
  const float* x    = (const float*)d_in[0];
  const float* gt   = (const float*)d_in[1];
  const float* Wih  = (const float*)d_in[2];
  const float* Whh  = (const float*)d_in[3];
  const float* bih  = (const float*)d_in[4];
  const float* bhh  = (const float*)d_in[5];
  const float* Wdec = (const float*)d_in[6];
  const float* bdec = (const float*)d_in[7];

  float* nll_part = (float*)d_ws;  // 512 floats, each written exactly once

  k_rec<<<dim3(32), dim3(512), 0, stream>>>(
      x, gt, Wih, Whh, bih, bhh, Wdec, bdec, nll_part);
  k_fin<<<dim3(1), dim3(512), 0, stream>>>(nll_part, (float*)d_out);
}

// Round 15
// 527.562 us; speedup vs baseline: 1.6010x; 1.6010x over previous
//
#include <hip/hip_runtime.h>
#include <stdint.h>

#define B_DIM 512
#define I_DIM 128
#define H_DIM 128
#define NSTEP 511   // reference scans t = 0..T-2

typedef __attribute__((ext_vector_type(4))) float f32x4;
typedef _Float16 half2_t __attribute__((ext_vector_type(2)));
typedef _Float16 half8_t __attribute__((ext_vector_type(8)));

// Barrier draining ONLY LDS ops; global prefetches stay in flight across it.
#define BAR_LDS() asm volatile("s_waitcnt lgkmcnt(0)\n\ts_barrier" ::: "memory")
#define MFMA16(A, B, C) __builtin_amdgcn_mfma_f32_16x16x32_f16(A, B, C, 0, 0, 0)

__device__ __forceinline__ float frcp(float v) {
#if __has_builtin(__builtin_amdgcn_rcpf)
  return __builtin_amdgcn_rcpf(v);
#else
  return 1.f / v;
#endif
}
__device__ __forceinline__ unsigned pkrtz_u(float a, float b) {
#if __has_builtin(__builtin_amdgcn_cvt_pkrtz)
  return __builtin_bit_cast(unsigned, __builtin_amdgcn_cvt_pkrtz(a, b));
#else
  half2_t r; r.x = (_Float16)a; r.y = (_Float16)b;
  return __builtin_bit_cast(unsigned, r);
#endif
}

// ---------------------------------------------------------------------------
// Persistent split-pipeline GRU: 32 blocks x 16 rows, 1024 threads = 16 waves
// (4/SIMD). Waves 0-7 = h-role (units 16w+l15): read pp (x-side preacts, one
// step stale) as MFMA C-init, 12 h-MFMAs, lean gate math (rcpf, biases in C),
// write f16 hnew. Waves 8-15 = x-role: stage x (2 steps ahead), 12 x-MFMAs
// with bias C-init, write pp[(i+1)&1]. x-work has no dependency on current h,
// so it fills the matrix/VALU pipes while h-waves' chains resolve.
// One lgkm-only barrier per step. Decode via 4 MFMAs on wave 0 (zero DS).
// ---------------------------------------------------------------------------
__global__ __launch_bounds__(1024, 4) void k_rec(
    const float* __restrict__ x, const float* __restrict__ gt,
    const float* __restrict__ Wih, const float* __restrict__ Whh,
    const float* __restrict__ bih, const float* __restrict__ bhh,
    const float* __restrict__ Wdec, const float* __restrict__ bdec,
    float* __restrict__ nll_part) {
  __shared__ __align__(16) _Float16 hT[2][16 * 128];   // 8 KB h tiles
  __shared__ __align__(16) _Float16 xT[2][16 * 128];   // 8 KB x tiles
  __shared__ __align__(16) float pp[2][3][4][128][4];  // 48 KB x-preacts
  __shared__ float gl[NSTEP * 16];                     // 32.7 KB gt slice

  const int tid = threadIdx.x;
  const int lane = tid & 63;
  const int w = tid >> 6;                  // 0..15
  const int l15 = lane & 15, l4 = lane >> 4;
  const int row0 = blockIdx.x * 16;

  // ---- gt preload (all threads) ----
#pragma unroll
  for (int q = 0; q < 8; ++q) {
    const int idx = tid + 1024 * q;
    if (idx < NSTEP * 16)
      gl[idx] = gt[(size_t)((idx >> 4) + 1) * B_DIM + row0 + (idx & 15)];
  }

  if (w < 8) {
    // =========================== h-role ===========================
    const int u = 16 * w + l15;

    half8_t bh[3][4];
#pragma unroll
    for (int g3 = 0; g3 < 3; ++g3)
#pragma unroll
      for (int ks = 0; ks < 4; ++ks) {
        const size_t off = (size_t)(g3 * H_DIM + u) * H_DIM + ks * 32 + l4 * 8;
        const float4 a = *(const float4*)(Whh + off);
        const float4 b = *(const float4*)(Whh + off + 4);
        half8_t v;
        v[0] = (_Float16)a.x; v[1] = (_Float16)a.y;
        v[2] = (_Float16)a.z; v[3] = (_Float16)a.w;
        v[4] = (_Float16)b.x; v[5] = (_Float16)b.y;
        v[6] = (_Float16)b.z; v[7] = (_Float16)b.w;
        bh[g3][ks] = v;
      }
    half8_t wdB[4];
#pragma unroll
    for (int ks = 0; ks < 4; ++ks) {
      half8_t v;
#pragma unroll
      for (int j = 0; j < 8; ++j)
        v[j] = (l15 == 0) ? (_Float16)Wdec[ks * 32 + l4 * 8 + j] : (_Float16)0.f;
      wdB[ks] = v;
    }
    const float bhn = bhh[2 * H_DIM + u];
    const float bd0 = bdec[0];
    const f32x4 cN = (f32x4){bhn, bhn, bhn, bhn};

    // zero h(0) tile (h-threads cover the 4 KB)
    *(uint2*)((char*)hT[0] + tid * 8) = (uint2){0u, 0u};

    float h_old[4] = {0.f, 0.f, 0.f, 0.f};
    float nllA[4] = {0.f, 0.f, 0.f, 0.f};
    __syncthreads();   // A: hT[0] + xT staged
    __syncthreads();   // B: pp[0] ready

#pragma unroll 1
    for (int i = 0; i < NSTEP; ++i) {
      const char* hb = (const char*)hT[i & 1];
      half8_t ah[4];
#pragma unroll
      for (int ks = 0; ks < 4; ++ks)
        ah[ks] = *(const half8_t*)(hb + l15 * 256 +
                                   ((((ks << 2) | l4) ^ l15) << 4));
      // x-side preacts as MFMA C-init (biases already folded by x-role)
      f32x4 aR = *(const f32x4*)&pp[i & 1][0][l4][u][0];
      f32x4 aZ = *(const f32x4*)&pp[i & 1][1][l4][u][0];
      const f32x4 pN = *(const f32x4*)&pp[i & 1][2][l4][u][0];
      f32x4 aN = cN;
#pragma unroll
      for (int ks = 0; ks < 4; ++ks) {
        aR = MFMA16(ah[ks], bh[0][ks], aR);
        aZ = MFMA16(ah[ks], bh[1][ks], aZ);
        aN = MFMA16(ah[ks], bh[2][ks], aN);
      }

      // decode + NLL for h(i) vs gt[i] (wave 0; epilogue covers h(511))
      if (w == 0 && i > 0) {
        f32x4 aD = (f32x4){0.f, 0.f, 0.f, 0.f};
#pragma unroll
        for (int ks = 0; ks < 4; ++ks) aD = MFMA16(ah[ks], wdB[ks], aD);
        if (l15 == 0) {
#pragma unroll
          for (int r = 0; r < 4; ++r) {
            const float C = frcp(1.f + __expf(-(aD[r] + bd0)));
            const float g = gl[(i - 1) * 16 + 4 * l4 + r];
            nllA[r] -= g * __logf(C + 1e-4f) +
                       (1.f - g) * __logf(1.f - C + 1e-4f);
          }
        }
      }

      // lean gate math; write hnew f16 into the other h tile
      char* hw = (char*)hT[(i + 1) & 1];
#pragma unroll
      for (int r = 0; r < 4; ++r) {
        const float r_ = frcp(1.f + __expf(-aR[r]));
        const float z_ = frcp(1.f + __expf(-aZ[r]));
        const float a2 = pN[r] + r_ * aN[r];
        const float n_ = 1.f - 2.f * frcp(__expf(2.f * a2) + 1.f);
        const float hnew = n_ + z_ * (h_old[r] - n_);
        h_old[r] = hnew;
        const int b = 4 * l4 + r;
        *(_Float16*)(hw + b * 256 + (((u >> 3) ^ b) << 4) + (u & 7) * 2) =
            (_Float16)hnew;
      }
      BAR_LDS();
    }

    // epilogue: decode h(511) vs gt[511]
    if (w == 0) {
      const char* hb = (const char*)hT[NSTEP & 1];
      half8_t ah[4];
#pragma unroll
      for (int ks = 0; ks < 4; ++ks)
        ah[ks] = *(const half8_t*)(hb + l15 * 256 +
                                   ((((ks << 2) | l4) ^ l15) << 4));
      f32x4 aD = (f32x4){0.f, 0.f, 0.f, 0.f};
#pragma unroll
      for (int ks = 0; ks < 4; ++ks) aD = MFMA16(ah[ks], wdB[ks], aD);
      if (l15 == 0) {
#pragma unroll
        for (int r = 0; r < 4; ++r) {
          const float C = frcp(1.f + __expf(-(aD[r] + bd0)));
          const float g = gl[(NSTEP - 1) * 16 + 4 * l4 + r];
          nllA[r] -= g * __logf(C + 1e-4f) +
                     (1.f - g) * __logf(1.f - C + 1e-4f);
          nll_part[row0 + 4 * l4 + r] = nllA[r];
        }
      }
    }
  } else {
    // =========================== x-role ===========================
    const int u = 16 * (w - 8) + l15;

    half8_t bx[3][4];
#pragma unroll
    for (int g3 = 0; g3 < 3; ++g3)
#pragma unroll
      for (int ks = 0; ks < 4; ++ks) {
        const size_t off = (size_t)(g3 * H_DIM + u) * H_DIM + ks * 32 + l4 * 8;
        const float4 a = *(const float4*)(Wih + off);
        const float4 b = *(const float4*)(Wih + off + 4);
        half8_t v;
        v[0] = (_Float16)a.x; v[1] = (_Float16)a.y;
        v[2] = (_Float16)a.z; v[3] = (_Float16)a.w;
        v[4] = (_Float16)b.x; v[5] = (_Float16)b.y;
        v[6] = (_Float16)b.z; v[7] = (_Float16)b.w;
        bx[g3][ks] = v;
      }
    const float brz0 = bih[u] + bhh[u];
    const float brz1 = bih[H_DIM + u] + bhh[H_DIM + u];
    const float bxn = bih[2 * H_DIM + u];
    const f32x4 cR = (f32x4){brz0, brz0, brz0, brz0};
    const f32x4 cZ = (f32x4){brz1, brz1, brz1, brz1};
    const f32x4 cXN = (f32x4){bxn, bxn, bxn, bxn};

    // staging identity (512 x-threads cover the 16x128 tile)
    const int xt = tid - 512;
    const int sxr = xt >> 5, scq = xt & 31;
    const int sbyte = sxr * 256 + (((scq >> 1) ^ sxr) << 4) + (scq & 1) * 8;
    const size_t xlbase = ((size_t)row0 + sxr) * I_DIM + 4 * scq;

    // stage x(0), x(1); preload x(2)
    {
      const float4 v0 = *(const float4*)&x[xlbase];
      const float4 v1 = *(const float4*)&x[(size_t)B_DIM * I_DIM + xlbase];
      uint2 p;
      p.x = pkrtz_u(v0.x, v0.y);
      p.y = pkrtz_u(v0.z, v0.w);
      *(uint2*)((char*)xT[0] + sbyte) = p;
      p.x = pkrtz_u(v1.x, v1.y);
      p.y = pkrtz_u(v1.z, v1.w);
      *(uint2*)((char*)xT[1] + sbyte) = p;
    }
    float4 xA = *(const float4*)&x[(size_t)2 * B_DIM * I_DIM + xlbase];
    __syncthreads();   // A: xT[0], xT[1] staged

    // pp[0] = x-part preacts for step 0 (from xT[0])
    {
      const char* xb = (const char*)xT[0];
      half8_t af[4];
#pragma unroll
      for (int ks = 0; ks < 4; ++ks)
        af[ks] = *(const half8_t*)(xb + l15 * 256 +
                                   ((((ks << 2) | l4) ^ l15) << 4));
      f32x4 aR = cR, aZ = cZ, aN = cXN;
#pragma unroll
      for (int ks = 0; ks < 4; ++ks) {
        aR = MFMA16(af[ks], bx[0][ks], aR);
        aZ = MFMA16(af[ks], bx[1][ks], aZ);
        aN = MFMA16(af[ks], bx[2][ks], aN);
      }
      *(f32x4*)&pp[0][0][l4][u][0] = aR;
      *(f32x4*)&pp[0][1][l4][u][0] = aZ;
      *(f32x4*)&pp[0][2][l4][u][0] = aN;
    }
    __syncthreads();   // B: pp[0] ready

#pragma unroll 1
    for (int i = 0; i < NSTEP; ++i) {
      // x-part preacts for step i+1 (from xT[(i+1)&1], staged at iter i-1)
      const char* xb = (const char*)xT[(i + 1) & 1];
      half8_t af[4];
#pragma unroll
      for (int ks = 0; ks < 4; ++ks)
        af[ks] = *(const half8_t*)(xb + l15 * 256 +
                                   ((((ks << 2) | l4) ^ l15) << 4));
      f32x4 aR = cR, aZ = cZ, aN = cXN;
#pragma unroll
      for (int ks = 0; ks < 4; ++ks) {
        aR = MFMA16(af[ks], bx[0][ks], aR);
        aZ = MFMA16(af[ks], bx[1][ks], aZ);
        aN = MFMA16(af[ks], bx[2][ks], aN);
      }
      *(f32x4*)&pp[(i + 1) & 1][0][l4][u][0] = aR;
      *(f32x4*)&pp[(i + 1) & 1][1][l4][u][0] = aZ;
      *(f32x4*)&pp[(i + 1) & 1][2][l4][u][0] = aN;

      // stage x(i+2) from xA; issue load for x(i+3)
      {
        uint2 p;
        p.x = pkrtz_u(xA.x, xA.y);
        p.y = pkrtz_u(xA.z, xA.w);
        *(uint2*)((char*)xT[i & 1] + sbyte) = p;
        const int nf = (i + 3 < 512) ? i + 3 : 511;
        xA = *(const float4*)&x[(size_t)nf * B_DIM * I_DIM + xlbase];
      }
      BAR_LDS();
    }
  }
}

// ---------------------------------------------------------------------------
__global__ __launch_bounds__(512) void k_fin(const float* __restrict__ nll_part,
                                             float* __restrict__ out) {
  __shared__ float red[8];
  const int tid = threadIdx.x;
  float v = nll_part[tid];
#pragma unroll
  for (int off = 32; off; off >>= 1) v += __shfl_down(v, off);
  if ((tid & 63) == 0) red[tid >> 6] = v;
  __syncthreads();
  if (tid == 0) {
    float s = 0.f;
#pragma unroll
    for (int i = 0; i < 8; ++i) s += red[i];
    out[0] = s * (1.f / (512.f * 512.f));
  }
}

// ---------------------------------------------------------------------------
extern "C" void kernel_launch(void* const* d_in, const int* in_sizes, int n_in,
                              void* d_out, int out_size, void* d_ws,
                              size_t ws_size, hipStream_t stream) {
  const float* x    = (const float*)d_in[0];
  const float* gt   = (const float*)d_in[1];
  const float* Wih  = (const float*)d_in[2];
  const float* Whh  = (const float*)d_in[3];
  const float* bih  = (const float*)d_in[4];
  const float* bhh  = (const float*)d_in[5];
  const float* Wdec = (const float*)d_in[6];
  const float* bdec = (const float*)d_in[7];

  float* nll_part = (float*)d_ws;  // 512 floats, each written exactly once

  k_rec<<<dim3(32), dim3(1024), 0, stream>>>(
      x, gt, Wih, Whh, bih, bhh, Wdec, bdec, nll_part);
  k_fin<<<dim3(1), dim3(512), 0, stream>>>(nll_part, (float*)d_out);
}